// Round 8
// baseline (482.839 us; speedup 1.0000x reference)
//
#include <hip/hip_runtime.h>

#define IDIM 512
#define MIXD 32
#define HID 96
#define BB 256
#define TT 512

typedef float f32x2 __attribute__((ext_vector_type(2)));
typedef float f32x4 __attribute__((ext_vector_type(4)));

// v_exp_f32: D = 2^S0
#define EXP2(x) __builtin_amdgcn_exp2f(x)

// DPP row_shl:N add on the VALU pipe (not the shared LDS pipe).
template <int CTRL>
__device__ __forceinline__ float dpp_shl_add(float x) {
    int m = __builtin_amdgcn_update_dpp(0, __float_as_int(x), CTRL, 0xf, 0xf, true);
    return x + __int_as_float(m);
}
// Reduce 8 consecutive lanes (octet) into the octet's lane 0.
__device__ __forceinline__ float octet_reduce_lane0(float x) {
    x = dpp_shl_add<0x104>(x);   // row_shl:4
    x = dpp_shl_add<0x102>(x);   // row_shl:2
    x = dpp_shl_add<0x101>(x);   // row_shl:1
    return x;
}
// Reduce each 16-lane DPP row into its lane 0.
__device__ __forceinline__ float red16(float x) {
    x = dpp_shl_add<0x108>(x);   // row_shl:8
    x = dpp_shl_add<0x104>(x);   // row_shl:4
    x = dpp_shl_add<0x102>(x);   // row_shl:2
    x = dpp_shl_add<0x101>(x);   // row_shl:1
    return x;
}

// ---------------- K1: z = x @ W_mix^T -----------------------------------
// Memory-bound (268 MB x). W RESIDENT IN REGISTERS (the R7 failure was
// wave-uniform W -> s_load chains -> lgkmcnt(0) drain stalls; LDS-broadcast
// alternatives are ds-instruction-bound). Thread (ks, mg, rr):
//   ks = tid&15  : k-slice [32ks, 32ks+32)
//   mg = tid>>4&7: m-group [4mg, 4mg+4)   -> W regs 4x32 = 128 VGPR
//   rr = tid>>7  : row-half (128 rows each)
// Per row: 8 global_load_dwordx4 (row r+1 prefetched during row r's FMAs,
// vmcnt-pipelined; no LDS, no barriers), 64 pk_fma, 4x red16 DPP reduce,
// ks==0 lanes store f32x4 (4 lanes x 16 B = contiguous 64 B per wave).
__global__ __launch_bounds__(256, 2) void k_mix(const float* __restrict__ x,
                                                const float* __restrict__ Wmix,
                                                float* __restrict__ z) {
    const int tid = threadIdx.x;
    const int ks  = tid & 15;
    const int mg  = (tid >> 4) & 7;
    const int rr  = tid >> 7;

    // ---- W tile into registers: 4 m-rows x 32 k ----
    f32x2 wr[4][16];
    #pragma unroll
    for (int mm = 0; mm < 4; ++mm) {
        const float* wp = Wmix + (size_t)(4 * mg + mm) * IDIM + 32 * ks;
        #pragma unroll
        for (int u = 0; u < 8; ++u) {
            f32x4 v = *(const f32x4*)(wp + 4 * u);
            wr[mm][2*u] = v.xy; wr[mm][2*u+1] = v.zw;
        }
    }

    const long rbase = (long)blockIdx.x * 256 + (long)rr * 128;
    const float* xp = x + rbase * IDIM + 32 * ks;
    float* zp = z + rbase * MIXD + 4 * mg;

    f32x4 xv[8];
    #pragma unroll
    for (int u = 0; u < 8; ++u) xv[u] = *(const f32x4*)(xp + 4 * u);

    for (int r = 0; r < 128; ++r) {
        // prefetch next row while this row computes (vmcnt hides HBM latency)
        f32x4 xn[8];
        if (r + 1 < 128) {
            const float* xq = xp + (size_t)(r + 1) * IDIM;
            #pragma unroll
            for (int u = 0; u < 8; ++u) xn[u] = *(const f32x4*)(xq + 4 * u);
        }

        f32x2 a0 = {0.f,0.f}, a1 = {0.f,0.f}, a2 = {0.f,0.f}, a3 = {0.f,0.f};
        #pragma unroll
        for (int u = 0; u < 8; ++u) {
            const f32x2 lo = xv[u].xy, hi = xv[u].zw;
            a0 = __builtin_elementwise_fma(wr[0][2*u], lo, a0);
            a0 = __builtin_elementwise_fma(wr[0][2*u+1], hi, a0);
            a1 = __builtin_elementwise_fma(wr[1][2*u], lo, a1);
            a1 = __builtin_elementwise_fma(wr[1][2*u+1], hi, a1);
            a2 = __builtin_elementwise_fma(wr[2][2*u], lo, a2);
            a2 = __builtin_elementwise_fma(wr[2][2*u+1], hi, a2);
            a3 = __builtin_elementwise_fma(wr[3][2*u], lo, a3);
            a3 = __builtin_elementwise_fma(wr[3][2*u+1], hi, a3);
        }
        float s0 = red16(a0.x + a0.y);
        float s1 = red16(a1.x + a1.y);
        float s2 = red16(a2.x + a2.y);
        float s3 = red16(a3.x + a3.y);
        if (ks == 0) {
            f32x4 o = { s0, s1, s2, s3 };
            *(f32x4*)(zp + (size_t)r * MIXD) = o;
        }
        #pragma unroll
        for (int u = 0; u < 8; ++u) xv[u] = xn[u];
    }
}

// ---------------- K2: GRU scan + head, 1 batch element per block ------------
// (unchanged from R7 — isolating the k_mix rewrite this round)
__global__ __launch_bounds__(768) void k_scan(const float* __restrict__ z,
                                              const float* __restrict__ Wih,
                                              const float* __restrict__ Whh,
                                              const float* __restrict__ bih,
                                              const float* __restrict__ bhh,
                                              const float* __restrict__ Whead,
                                              const float* __restrict__ bhead,
                                              const float* __restrict__ Wmix,
                                              float* __restrict__ y) {
    const int b   = blockIdx.x;
    const int tid = threadIdx.x;
    const int j   = tid >> 3;     // 0..95
    const int o   = tid & 7;      // 0..7
    const float L  = 1.4426950408889634f;   // log2(e)
    const float L2 = 2.8853900817779268f;   // 2*log2(e)

    __shared__ __align__(16) float sz[256 * MIXD];   // 32 KB: half of the z row
    __shared__ __align__(16) float shp[2][HID];      // h ping-pong
    __shared__ __align__(16) float szn[MIXD];

    f32x2 whr[6], whu[6], whn[6], wir[2], wiu[2], win[2];
    #pragma unroll
    for (int c = 0; c < 3; ++c) {
        f32x4 v = *(const f32x4*)(Whh + (size_t)(j        ) * HID + o * 12 + c * 4);
        v *= L;  whr[2*c] = v.xy; whr[2*c+1] = v.zw;
    }
    #pragma unroll
    for (int c = 0; c < 3; ++c) {
        f32x4 v = *(const f32x4*)(Whh + (size_t)(j +   HID) * HID + o * 12 + c * 4);
        v *= L;  whu[2*c] = v.xy; whu[2*c+1] = v.zw;
    }
    #pragma unroll
    for (int c = 0; c < 3; ++c) {
        f32x4 v = *(const f32x4*)(Whh + (size_t)(j + 2*HID) * HID + o * 12 + c * 4);
        v *= L2; whn[2*c] = v.xy; whn[2*c+1] = v.zw;
    }
    {
        f32x4 v = *(const f32x4*)(Wih + (size_t)(j        ) * MIXD + o * 4);
        v *= L;  wir[0] = v.xy; wir[1] = v.zw;
    }
    {
        f32x4 v = *(const f32x4*)(Wih + (size_t)(j +   HID) * MIXD + o * 4);
        v *= L;  wiu[0] = v.xy; wiu[1] = v.zw;
    }
    {
        f32x4 v = *(const f32x4*)(Wih + (size_t)(j + 2*HID) * MIXD + o * 4);
        v *= L2; win[0] = v.xy; win[1] = v.zw;
    }
    float br = 0.f, bu = 0.f, bxn = 0.f, bhn = 0.f;
    if (o == 0) {
        br  = L  * (bih[j]       + bhh[j]);
        bu  = L  * (bih[j + HID] + bhh[j + HID]);
        bxn = L2 * bih[j + 2*HID];
        bhn = L2 * bhh[j + 2*HID];
    }

    if (tid < HID) shp[0][tid] = 0.f;

    const f32x4* zb4 = (const f32x4*)(z + (size_t)b * TT * MIXD);
    f32x4* sz4 = (f32x4*)sz;

    for (int c = 0; c < TT / 256; ++c) {
        for (int idx = tid; idx < 2048; idx += 768)
            sz4[idx] = zb4[c * 2048 + idx];
        __syncthreads();

        #pragma unroll 2
        for (int tt = 0; tt < 256; ++tt) {
            const int t = (c << 8) + tt;
            const float* hr = shp[t & 1];
            float*       hw = shp[(t + 1) & 1];
            const float* zrow = sz + tt * MIXD;

            const f32x4 z4 = *(const f32x4*)(zrow + o * 4);
            const f32x4 h0 = *(const f32x4*)(hr + o * 12);
            const f32x4 h1 = *(const f32x4*)(hr + o * 12 + 4);
            const f32x4 h2 = *(const f32x4*)(hr + o * 12 + 8);
            const float hold = hr[j];

            f32x2 aR  = {br,  0.f}, aU  = {bu,  0.f};
            f32x2 aXN = {bxn, 0.f}, aHN = {bhn, 0.f};

            aR  = __builtin_elementwise_fma(wir[0], z4.xy, aR);
            aR  = __builtin_elementwise_fma(wir[1], z4.zw, aR);
            aU  = __builtin_elementwise_fma(wiu[0], z4.xy, aU);
            aU  = __builtin_elementwise_fma(wiu[1], z4.zw, aU);
            aXN = __builtin_elementwise_fma(win[0], z4.xy, aXN);
            aXN = __builtin_elementwise_fma(win[1], z4.zw, aXN);

            const f32x2 hh[6] = { h0.xy, h0.zw, h1.xy, h1.zw, h2.xy, h2.zw };
            #pragma unroll
            for (int k = 0; k < 6; ++k) {
                aR  = __builtin_elementwise_fma(whr[k], hh[k], aR);
                aU  = __builtin_elementwise_fma(whu[k], hh[k], aU);
                aHN = __builtin_elementwise_fma(whn[k], hh[k], aHN);
            }

            float sR  = octet_reduce_lane0(aR.x  + aR.y);
            float sU  = octet_reduce_lane0(aU.x  + aU.y);
            float sXN = octet_reduce_lane0(aXN.x + aXN.y);
            float sHN = octet_reduce_lane0(aHN.x + aHN.y);

            float r = __builtin_amdgcn_rcpf(1.f + EXP2(-sR));
            float u = __builtin_amdgcn_rcpf(1.f + EXP2(-sU));
            float n = 1.f - 2.f * __builtin_amdgcn_rcpf(1.f + EXP2(sXN + r * sHN));
            float hnew = u * (hold - n) + n;
            if (o == 0) hw[j] = hnew;
            __syncthreads();
        }
    }

    // ---- fused head: zn = Whead @ h + bhead ; y = zn @ Wmix ----
    if (tid < MIXD) {
        const float* h = shp[0];
        float a0 = 0.f, a1 = 0.f, a2 = 0.f, a3 = 0.f;
        #pragma unroll
        for (int kc = 0; kc < HID / 4; ++kc) {
            f32x4 wv = *(const f32x4*)(Whead + (size_t)tid * HID + kc * 4);
            f32x4 hv = *(const f32x4*)(h + kc * 4);
            a0 += wv.x * hv.x; a1 += wv.y * hv.y;
            a2 += wv.z * hv.z; a3 += wv.w * hv.w;
        }
        szn[tid] = bhead[tid] + ((a0 + a1) + (a2 + a3));
    }
    __syncthreads();
    if (tid < IDIM) {
        float acc = 0.f;
        #pragma unroll
        for (int m = 0; m < MIXD; ++m)
            acc += szn[m] * Wmix[(size_t)m * IDIM + tid];
        y[(size_t)b * IDIM + tid] = acc;
    }
}

extern "C" void kernel_launch(void* const* d_in, const int* in_sizes, int n_in,
                              void* d_out, int out_size, void* d_ws, size_t ws_size,
                              hipStream_t stream) {
    const float* x     = (const float*)d_in[0];
    const float* Wmix  = (const float*)d_in[1];
    const float* Wih   = (const float*)d_in[2];
    const float* Whh   = (const float*)d_in[3];
    const float* bih   = (const float*)d_in[4];
    const float* bhh   = (const float*)d_in[5];
    const float* Whead = (const float*)d_in[6];
    const float* bhead = (const float*)d_in[7];
    float* out = (float*)d_out;

    float* z = (float*)d_ws;   // [B*T, 32] = 16.78 MB

    k_mix <<<512, 256, 0, stream>>>(x, Wmix, z);
    k_scan<<<BB,  768, 0, stream>>>(z, Wih, Whh, bih, bhh, Whead, bhead, Wmix, out);
}

// Round 9
// 425.410 us; speedup vs baseline: 1.1350x; 1.1350x over previous
//
#include <hip/hip_runtime.h>

#define IDIM 512
#define MIXD 32
#define HID 96
#define BB 256
#define TT 512

typedef float f32x2 __attribute__((ext_vector_type(2)));
typedef float f32x4 __attribute__((ext_vector_type(4)));

// v_exp_f32: D = 2^S0
#define EXP2(x) __builtin_amdgcn_exp2f(x)

// DPP row_shl:N add on the VALU pipe (not the shared LDS pipe).
template <int CTRL>
__device__ __forceinline__ float dpp_shl_add(float x) {
    int m = __builtin_amdgcn_update_dpp(0, __float_as_int(x), CTRL, 0xf, 0xf, true);
    return x + __int_as_float(m);
}
// Reduce 8 consecutive lanes (octet) into the octet's lane 0.
__device__ __forceinline__ float octet_reduce_lane0(float x) {
    x = dpp_shl_add<0x104>(x);   // row_shl:4
    x = dpp_shl_add<0x102>(x);   // row_shl:2
    x = dpp_shl_add<0x101>(x);   // row_shl:1
    return x;
}

// ---------------- K1: z = x @ W_mix^T  (reverted to the proven R0 form) -----
// One row (b,t) per thread; W reads wave-uniform -> scalar cache. Timed
// ~145 us historically (R2/R4 subtraction). The R7 (s_load-drain-stalled
// LDS version, 300 us) and R8 (8x x-re-read register version, ~230 us)
// rewrites were both slower.
__global__ __launch_bounds__(256) void k_mix(const float* __restrict__ x,
                                             const float* __restrict__ Wmix,
                                             float* __restrict__ z) {
    long row = (long)blockIdx.x * 256 + threadIdx.x;   // 131072 rows
    const float* xr = x + row * IDIM;
    float acc[MIXD];
    #pragma unroll
    for (int m = 0; m < MIXD; ++m) acc[m] = 0.f;
    for (int kc = 0; kc < IDIM / 4; ++kc) {
        float4 a = *(const float4*)(xr + kc * 4);
        #pragma unroll
        for (int m = 0; m < MIXD; ++m) {
            float4 w = *(const float4*)(Wmix + m * IDIM + kc * 4); // uniform -> s_load
            acc[m] += a.x * w.x + a.y * w.y + a.z * w.z + a.w * w.w;
        }
    }
    float* zr = z + row * MIXD;
    #pragma unroll
    for (int mc = 0; mc < MIXD / 4; ++mc) {
        float4 o;
        o.x = acc[mc*4+0]; o.y = acc[mc*4+1]; o.z = acc[mc*4+2]; o.w = acc[mc*4+3];
        *(float4*)(zr + mc * 4) = o;
    }
}

// ---------------- K2: GRU scan + head, 1 batch element per block ------------
// 256 threads = 4 waves = 1 wave/SIMD. Octet (8 lanes, o = tid&7) serves
// THREE h-indices j0, j0+32, j0+64 (j0 = tid>>3): the LDS reads (z row
// slice + h fragments) depend only on o, so they are read ONCE and reused
// for all 3 j's -> 3x less LDS pipe traffic than the 768-thread version.
// h[j] for the owner octet is kept in registers (hown[i], valid on lane
// o==0) so the update needs no LDS read at all. One barrier per step,
// zero global ops in the loop. Weights per thread: 72 f32x2 = 144 VGPR.
__global__ __launch_bounds__(256, 1) void k_scan(const float* __restrict__ z,
                                                 const float* __restrict__ Wih,
                                                 const float* __restrict__ Whh,
                                                 const float* __restrict__ bih,
                                                 const float* __restrict__ bhh,
                                                 const float* __restrict__ Whead,
                                                 const float* __restrict__ bhead,
                                                 const float* __restrict__ Wmix,
                                                 float* __restrict__ y) {
    const int b   = blockIdx.x;
    const int tid = threadIdx.x;
    const int j0  = tid >> 3;     // 0..31
    const int o   = tid & 7;      // 0..7
    const float L  = 1.4426950408889634f;   // log2(e)
    const float L2 = 2.8853900817779268f;   // 2*log2(e)

    __shared__ __align__(16) float sz[256 * MIXD];   // 32 KB: half of the z row
    __shared__ __align__(16) float shp[2][HID];      // h ping-pong
    __shared__ __align__(16) float szn[MIXD];

    // ---- weights for 3 j's into registers as f32x2, pre-scaled ----
    f32x2 whr[3][6], whu[3][6], whn[3][6], wir[3][2], wiu[3][2], win[3][2];
    float br[3], bu[3], bxn[3], bhn[3];
    #pragma unroll
    for (int i = 0; i < 3; ++i) {
        const int j = j0 + 32 * i;
        #pragma unroll
        for (int c = 0; c < 3; ++c) {
            f32x4 v = *(const f32x4*)(Whh + (size_t)(j        ) * HID + o * 12 + c * 4);
            v *= L;  whr[i][2*c] = v.xy; whr[i][2*c+1] = v.zw;
        }
        #pragma unroll
        for (int c = 0; c < 3; ++c) {
            f32x4 v = *(const f32x4*)(Whh + (size_t)(j +   HID) * HID + o * 12 + c * 4);
            v *= L;  whu[i][2*c] = v.xy; whu[i][2*c+1] = v.zw;
        }
        #pragma unroll
        for (int c = 0; c < 3; ++c) {
            f32x4 v = *(const f32x4*)(Whh + (size_t)(j + 2*HID) * HID + o * 12 + c * 4);
            v *= L2; whn[i][2*c] = v.xy; whn[i][2*c+1] = v.zw;
        }
        {
            f32x4 v = *(const f32x4*)(Wih + (size_t)(j        ) * MIXD + o * 4);
            v *= L;  wir[i][0] = v.xy; wir[i][1] = v.zw;
        }
        {
            f32x4 v = *(const f32x4*)(Wih + (size_t)(j +   HID) * MIXD + o * 4);
            v *= L;  wiu[i][0] = v.xy; wiu[i][1] = v.zw;
        }
        {
            f32x4 v = *(const f32x4*)(Wih + (size_t)(j + 2*HID) * MIXD + o * 4);
            v *= L2; win[i][0] = v.xy; win[i][1] = v.zw;
        }
        br[i]  = (o == 0) ? L  * (bih[j]       + bhh[j])       : 0.f;
        bu[i]  = (o == 0) ? L  * (bih[j + HID] + bhh[j + HID]) : 0.f;
        bxn[i] = (o == 0) ? L2 * bih[j + 2*HID] : 0.f;
        bhn[i] = (o == 0) ? L2 * bhh[j + 2*HID] : 0.f;
    }

    float hown[3] = { 0.f, 0.f, 0.f };   // h[j0+32i], valid on lane o==0
    if (tid < HID) shp[0][tid] = 0.f;    // h0 = 0 (covered by stage barrier)

    const f32x4* zb4 = (const f32x4*)(z + (size_t)b * TT * MIXD);
    f32x4* sz4 = (f32x4*)sz;

    for (int c = 0; c < TT / 256; ++c) {
        #pragma unroll
        for (int i = 0; i < 8; ++i)
            sz4[tid + 256 * i] = zb4[c * 2048 + tid + 256 * i];
        __syncthreads();

        for (int tt = 0; tt < 256; ++tt) {
            const int t = (c << 8) + tt;
            const float* hr = shp[t & 1];
            float*       hw = shp[(t + 1) & 1];

            // LDS reads: depend only on o -> shared across the 3 j's
            const f32x4 z4 = *(const f32x4*)(sz + tt * MIXD + o * 4);
            const f32x4 h0 = *(const f32x4*)(hr + o * 12);
            const f32x4 h1 = *(const f32x4*)(hr + o * 12 + 4);
            const f32x4 h2 = *(const f32x4*)(hr + o * 12 + 8);
            const f32x2 hh[6] = { h0.xy, h0.zw, h1.xy, h1.zw, h2.xy, h2.zw };

            float hv[3];
            #pragma unroll
            for (int i = 0; i < 3; ++i) {
                f32x2 aR  = {br[i],  0.f}, aU  = {bu[i],  0.f};
                f32x2 aXN = {bxn[i], 0.f}, aHN = {bhn[i], 0.f};

                aR  = __builtin_elementwise_fma(wir[i][0], z4.xy, aR);
                aR  = __builtin_elementwise_fma(wir[i][1], z4.zw, aR);
                aU  = __builtin_elementwise_fma(wiu[i][0], z4.xy, aU);
                aU  = __builtin_elementwise_fma(wiu[i][1], z4.zw, aU);
                aXN = __builtin_elementwise_fma(win[i][0], z4.xy, aXN);
                aXN = __builtin_elementwise_fma(win[i][1], z4.zw, aXN);

                #pragma unroll
                for (int k = 0; k < 6; ++k) {
                    aR  = __builtin_elementwise_fma(whr[i][k], hh[k], aR);
                    aU  = __builtin_elementwise_fma(whu[i][k], hh[k], aU);
                    aHN = __builtin_elementwise_fma(whn[i][k], hh[k], aHN);
                }

                float sR  = octet_reduce_lane0(aR.x  + aR.y);
                float sU  = octet_reduce_lane0(aU.x  + aU.y);
                float sXN = octet_reduce_lane0(aXN.x + aXN.y);
                float sHN = octet_reduce_lane0(aHN.x + aHN.y);

                float r = __builtin_amdgcn_rcpf(1.f + EXP2(-sR));
                float u = __builtin_amdgcn_rcpf(1.f + EXP2(-sU));
                float n = 1.f - 2.f * __builtin_amdgcn_rcpf(1.f + EXP2(sXN + r * sHN));
                hv[i] = u * (hown[i] - n) + n;   // lane0: correct; others: garbage
                hown[i] = hv[i];
            }
            if (o == 0) {
                hw[j0]      = hv[0];
                hw[j0 + 32] = hv[1];
                hw[j0 + 64] = hv[2];
            }
            __syncthreads();                    // the ONLY barrier per step
        }
    }

    // ---- fused head: zn = Whead @ h + bhead ; y = zn @ Wmix ----
    if (tid < MIXD) {
        const float* h = shp[0];                 // TT even -> final h in shp[0]
        float a0 = 0.f, a1 = 0.f, a2 = 0.f, a3 = 0.f;
        #pragma unroll
        for (int kc = 0; kc < HID / 4; ++kc) {
            f32x4 wv = *(const f32x4*)(Whead + (size_t)tid * HID + kc * 4);
            f32x4 hv4 = *(const f32x4*)(h + kc * 4);
            a0 += wv.x * hv4.x; a1 += wv.y * hv4.y;
            a2 += wv.z * hv4.z; a3 += wv.w * hv4.w;
        }
        szn[tid] = bhead[tid] + ((a0 + a1) + (a2 + a3));
    }
    __syncthreads();
    #pragma unroll
    for (int rep = 0; rep < 2; ++rep) {
        const int col = tid + 256 * rep;
        float acc = 0.f;
        #pragma unroll
        for (int m = 0; m < MIXD; ++m)
            acc += szn[m] * Wmix[(size_t)m * IDIM + col];
        y[(size_t)b * IDIM + col] = acc;
    }
}

extern "C" void kernel_launch(void* const* d_in, const int* in_sizes, int n_in,
                              void* d_out, int out_size, void* d_ws, size_t ws_size,
                              hipStream_t stream) {
    const float* x     = (const float*)d_in[0];
    const float* Wmix  = (const float*)d_in[1];
    const float* Wih   = (const float*)d_in[2];
    const float* Whh   = (const float*)d_in[3];
    const float* bih   = (const float*)d_in[4];
    const float* bhh   = (const float*)d_in[5];
    const float* Whead = (const float*)d_in[6];
    const float* bhead = (const float*)d_in[7];
    float* out = (float*)d_out;

    float* z = (float*)d_ws;   // [B*T, 32] = 16.78 MB

    k_mix <<<512, 256, 0, stream>>>(x, Wmix, z);
    k_scan<<<BB,  256, 0, stream>>>(z, Wih, Whh, bih, bhh, Whead, bhead, Wmix, out);
}